// Round 1
// baseline (145.817 us; speedup 1.0000x reference)
//
#include <hip/hip_runtime.h>
#include <hip/hip_bf16.h>

#define KDIM 256
#define NTOT 131072
#define PN 65536   // 256*256

typedef float f32x4 __attribute__((ext_vector_type(4)));
typedef __bf16 bf16x8 __attribute__((ext_vector_type(8)));

__device__ __forceinline__ unsigned short f2bf(float x){
  unsigned u = __float_as_uint(x);
  u += 0x7fffu + ((u >> 16) & 1u);   // round-to-nearest-even
  return (unsigned short)(u >> 16);
}
__device__ __forceinline__ unsigned pk2(float lo, float hi){
  return (unsigned)f2bf(lo) | ((unsigned)f2bf(hi) << 16);
}
// XOR swizzle for 64B rows: spreads both transpose-writes and b128 frag reads
__device__ __forceinline__ int swz(int i){ return (((i >> 1) ^ (i >> 4)) & 7) << 4; }

struct Stage { f32x4 a0, a1, a2, a3, b0, b1, b2, b3; };

__device__ __forceinline__ void stage_load(Stage& s, const float* pa, const float* pb, long off){
  s.a0 = *(const f32x4*)(pa + off);
  s.a1 = *(const f32x4*)(pa + off + 4);
  s.a2 = *(const f32x4*)(pa + off + KDIM);
  s.a3 = *(const f32x4*)(pa + off + KDIM + 4);
  s.b0 = *(const f32x4*)(pb + off);
  s.b1 = *(const f32x4*)(pb + off + 4);
  s.b2 = *(const f32x4*)(pb + off + KDIM);
  s.b3 = *(const f32x4*)(pb + off + KDIM + 4);
}

__device__ __forceinline__ void stage_store(const Stage& s, char* As, char* Bs, const int* offW){
#pragma unroll
  for (int m = 0; m < 8; ++m){
    float alo = (m < 4) ? s.a0[m] : s.a1[m - 4];
    float ahi = (m < 4) ? s.a2[m] : s.a3[m - 4];
    *(unsigned*)(As + offW[m]) = pk2(alo, ahi);
    float blo = (m < 4) ? s.b0[m] : s.b1[m - 4];
    float bhi = (m < 4) ? s.b2[m] : s.b3[m - 4];
    *(unsigned*)(Bs + offW[m]) = pk2(blo, bhi);
  }
}

__device__ __forceinline__ void compute_t(const char* As, const char* Bs,
                                          const int* offA, const int* offB,
                                          f32x4 (&acc)[4][8])
{
  bf16x8 af[4], bfr[8];
#pragma unroll
  for (int m = 0; m < 4; ++m) af[m] = *(const bf16x8*)(As + offA[m]);
#pragma unroll
  for (int n = 0; n < 8; ++n) bfr[n] = *(const bf16x8*)(Bs + offB[n]);
#pragma unroll
  for (int m = 0; m < 4; ++m)
#pragma unroll
    for (int n = 0; n < 8; ++n)
      acc[m][n] = __builtin_amdgcn_mfma_f32_16x16x32_bf16(af[m], bfr[n], acc[m][n], 0, 0, 0);
}

// K1: partial P_b[256][256] = sum over this block's N-chunk of v1[n][i]*v2[n][j]
__global__ __launch_bounds__(512) void k_gemm(const float* __restrict__ v1,
                                              const float* __restrict__ v2,
                                              float* __restrict__ part,
                                              int rowsPerBlock)
{
  __shared__ char sm[32768];       // A: [256 rows][64B], B same at +16KB (BK=32 bf16)
  char* As = sm;
  char* Bs = sm + 16384;
  const int t    = threadIdx.x;
  const int b    = blockIdx.x;
  const int lane = t & 63, wid = t >> 6;
  const int di   = lane & 15, g = lane >> 4;
  const int i0w  = (wid >> 1) * 64;   // 4 wave-rows  x 64 i
  const int j0w  = (wid & 1) * 128;   // 2 wave-cols  x 128 j
  const int rp   = t >> 5;            // 0..15  (row-pair of chunk)
  const int c0   = (t & 31) * 8;      // 8-col group
  const int n2   = rp * 2;

  int offW[8], offA[4], offB[8];
#pragma unroll
  for (int m = 0; m < 8; ++m){ int i = c0 + m;        offW[m] = ((i << 6) + (rp << 2)) ^ swz(i); }
#pragma unroll
  for (int m = 0; m < 4; ++m){ int i = i0w + 16*m + di; offA[m] = ((i << 6) + (g << 4)) ^ swz(i); }
#pragma unroll
  for (int n = 0; n < 8; ++n){ int j = j0w + 16*n + di; offB[n] = ((j << 6) + (g << 4)) ^ swz(j); }

  f32x4 acc[4][8];
#pragma unroll
  for (int m = 0; m < 4; ++m)
#pragma unroll
    for (int n = 0; n < 8; ++n){ f32x4 z = {0.f, 0.f, 0.f, 0.f}; acc[m][n] = z; }

  const long rowBase = (long)b * rowsPerBlock;
  const float* pa = v1 + (rowBase + n2) * KDIM + c0;
  const float* pb = v2 + (rowBase + n2) * KDIM + c0;
  const int nIter = rowsPerBlock >> 6;   // two BK=32 chunks per iteration

  Stage s0, s1;
  stage_load(s0, pa, pb, 0);
  for (int it = 0; it < nIter; ++it){
    const long base = (long)it * 2 * (32 * KDIM);
    stage_load(s1, pa, pb, base + 32 * KDIM);       // prefetch chunk 2it+1
    stage_store(s0, As, Bs, offW);
    __syncthreads();
    compute_t(As, Bs, offA, offB, acc);
    __syncthreads();
    if (it + 1 < nIter) stage_load(s0, pa, pb, base + 64 * KDIM);  // prefetch 2it+2
    stage_store(s1, As, Bs, offW);
    __syncthreads();
    compute_t(As, Bs, offA, offB, acc);
    __syncthreads();
  }

  float* op = part + (long)b * PN;
#pragma unroll
  for (int m = 0; m < 4; ++m)
#pragma unroll
    for (int n = 0; n < 8; ++n){
      const int i = i0w + 16*m + 4*g;
      const int j = j0w + 16*n + di;
#pragma unroll
      for (int r = 0; r < 4; ++r)
        op[(long)(i + r) * KDIM + j] = acc[m][n][r];
    }
}

// K2: P = sum_b part_b ; also row sums r[g] and (atomic) col sums c[j]
__global__ __launch_bounds__(1024) void k_reduce(const float* __restrict__ part,
                                                 float* __restrict__ P,
                                                 float* __restrict__ rsum,
                                                 float* __restrict__ csum,
                                                 int NB)
{
  __shared__ float red[1024];
  const int gr = blockIdx.x;     // P row
  const int t  = threadIdx.x;
  const int j  = t & 255, q = t >> 8;   // 4-way split over partial buffers
  const int bpq = NB >> 2;
  float s = 0.f;
  const float* p = part + (long)(q * bpq) * PN + gr * KDIM + j;
  for (int b = 0; b < bpq; ++b) s += p[(long)b * PN];
  red[t] = s; __syncthreads();
  if (t < 512) red[t] += red[t + 512];
  __syncthreads();
  float v = 0.f;
  if (t < 256){
    v = red[t] + red[t + 256];
    P[gr * KDIM + t] = v;
    atomicAdd(&csum[t], v);
  }
  __syncthreads();
  red[t] = (t < 256) ? v : 0.f;
  __syncthreads();
  for (int st = 128; st > 0; st >>= 1){
    if (t < st) red[t] += red[t + st];
    __syncthreads();
  }
  if (t == 0) rsum[gr] = red[0];
}

// K3: S = sum r ; lm[i] = log((r_i + c_i)/(2S)) ; scal[0] = 1/(2S)
__global__ __launch_bounds__(256) void k_marg(const float* __restrict__ rsum,
                                              const float* __restrict__ csum,
                                              float* __restrict__ lm,
                                              float* __restrict__ scal)
{
  __shared__ float red[256];
  const int i = threadIdx.x;
  float ri = rsum[i];
  red[i] = ri; __syncthreads();
  for (int st = 128; st > 0; st >>= 1){
    if (i < st) red[i] += red[i + st];
    __syncthreads();
  }
  const float S = red[0];
  const float inv2S = 0.5f / S;
  float mi = (ri + csum[i]) * inv2S;
  mi = fmaxf(mi, 2.220446049250313e-16f);
  lm[i] = logf(mi);
  if (i == 0) scal[0] = inv2S;
}

// K4: loss = sum_ij -q*(log q - 10*(lm_i + lm_j)),  q = (P_ij + P_ji)/(2S)
__global__ __launch_bounds__(1024) void k_loss(const float* __restrict__ P,
                                               const float* __restrict__ lm,
                                               const float* __restrict__ scal,
                                               float* __restrict__ out)
{
  __shared__ float red[1024];
  const float inv2S = scal[0];
  float acc = 0.f;
  for (int e = threadIdx.x; e < PN; e += 1024){
    const int i = e >> 8, j = e & 255;
    float q = (P[i * KDIM + j] + P[j * KDIM + i]) * inv2S;
    q = fmaxf(q, 2.220446049250313e-16f);
    acc += -q * (logf(q) - 10.0f * (lm[i] + lm[j]));
  }
  red[threadIdx.x] = acc; __syncthreads();
  for (int st = 512; st > 0; st >>= 1){
    if (threadIdx.x < st) red[threadIdx.x] += red[threadIdx.x + st];
    __syncthreads();
  }
  if (threadIdx.x == 0) out[0] = red[0];
}

extern "C" void kernel_launch(void* const* d_in, const int* in_sizes, int n_in,
                              void* d_out, int out_size, void* d_ws, size_t ws_size,
                              hipStream_t stream) {
  const float* v1 = (const float*)d_in[0];
  const float* v2 = (const float*)d_in[1];
  float* out = (float*)d_out;
  float* ws  = (float*)d_ws;

  // choose number of split-K blocks to fit partials in workspace
  const size_t availF = ws_size / 4;
  int NB = 256;
  while (NB > 4 && (size_t)NB * PN + PN + 1024 > availF) NB >>= 1;
  const int rowsPerBlock = NTOT / NB;

  float* part = ws;
  float* P    = ws + (size_t)NB * PN;
  float* rsum = P + PN;
  float* csum = rsum + 256;
  float* lm   = csum + 256;
  float* scal = lm + 256;

  hipMemsetAsync(csum, 0, 256 * sizeof(float), stream);
  k_gemm  <<<NB, 512, 0, stream>>>(v1, v2, part, rowsPerBlock);
  k_reduce<<<256, 1024, 0, stream>>>(part, P, rsum, csum, NB);
  k_marg  <<<1, 256, 0, stream>>>(rsum, csum, lm, scal);
  k_loss  <<<1, 1024, 0, stream>>>(P, lm, scal, out);
}